// Round 3
// baseline (479.649 us; speedup 1.0000x reference)
//
#include <hip/hip_runtime.h>
#include <hip/hip_bf16.h>
#include <float.h>

#define K_NEI 9
#define M 4096
#define N 65536
#define D 128
#define SEGS 16
#define SEG_LEN (N / SEGS)     // 4096 bank rows per segment
#define QB 128                 // queries per block
#define BB 128                 // bank rows per chunk
#define CHUNKS (SEG_LEN / BB)  // 32

typedef __bf16 bf16x8 __attribute__((ext_vector_type(8)));
typedef float floatx4 __attribute__((ext_vector_type(4)));

static __device__ inline floatx4 mfma16(bf16x8 a, bf16x8 b, floatx4 c) {
    return __builtin_amdgcn_mfma_f32_16x16x32_bf16(a, b, c, 0, 0, 0);
}

// async global->LDS, 16B per lane, dest = lds_base + lane*16
#define GL_LDS16(gp, lp)                                                     \
    __builtin_amdgcn_global_load_lds(                                        \
        (const __attribute__((address_space(1))) unsigned int*)(const void*)(gp), \
        (__attribute__((address_space(3))) unsigned int*)(void*)(lp), 16, 0, 0)

// ---------------------------------------------------------------------------
// Kernel 1: fp32 -> bf16 convert + row sum-of-squares (wave per row)
// ---------------------------------------------------------------------------
__global__ void prep_kernel(const float* __restrict__ x,
                            __hip_bfloat16* __restrict__ xb,
                            float* __restrict__ sq, int rows) {
    int wave = (int)((blockIdx.x * blockDim.x + threadIdx.x) >> 6);
    int lane = threadIdx.x & 63;
    if (wave >= rows) return;
    float2 v = ((const float2*)(x + (size_t)wave * D))[lane];
    float s = v.x * v.x + v.y * v.y;
    __hip_bfloat16* dst = xb + (size_t)wave * D + lane * 2;
    dst[0] = __float2bfloat16(v.x);
    dst[1] = __float2bfloat16(v.y);
#pragma unroll
    for (int off = 32; off > 0; off >>= 1) s += __shfl_down(s, off, 64);
    if (lane == 0) sq[wave] = s;
}

// ---------------------------------------------------------------------------
// Kernel 2: MFMA distance GEMM + fused per-query top-9 (per bank segment)
// grid = 512 blocks of 256 threads (4 waves); XCD-swizzled so the 32 blocks
// sharing a bank segment land on one XCD (blockIdx%8 == seg%8).
//
// acc is initialized to -0.5*bs (fp32, prescaled in LDS), so after K=128:
//   acc = dot - 0.5*bs   =>   d2 = qs - 2*acc          (exact fp32 norms)
// Gate test per element: d2 <= g  <=>  acc >= h, h = 0.5*(qs - g): 1 v_cmp.
// g = min(own t9[8], device-global thr_g[q]) -- atomicMin-published, agent-
// scope loaded. Stale-high gates are safe (only prune provably-out items);
// '<=' insert handles cross-stream ties exactly (a publisher whose 9th == v
// either holds all needed copies of v or its published thr > v).
// ---------------------------------------------------------------------------
__global__ __launch_bounds__(256, 2)
void knn_main(const __hip_bfloat16* __restrict__ bankbf,
              const __hip_bfloat16* __restrict__ featbf,
              const float* __restrict__ bsqp,
              const float* __restrict__ qsqp,
              int* __restrict__ thr_g,
              float* __restrict__ part) {
    __shared__ __align__(16) union SMEM {
        struct {
            short bt[32 * 512];   // 32 KB: 32 regions (bt 0..7 x ks 0..3) x 64 lanes x 8 bf16
            float nsq[SEG_LEN];   // 16 KB: -0.5 * bank norms for this segment
        };
        float merge[QB][8 * K_NEI];  // 36.9 KB epilogue merge buffer
    } sm;

    const int tid  = threadIdx.x;
    const int lane = tid & 63;
    const int wv   = tid >> 6;
    const int qw   = wv & 1;        // query half of block
    const int bw   = wv >> 1;       // bank half of chunk
    // XCD swizzle: seg%8 == blockIdx%8
    const int s8  = blockIdx.x & 7;
    const int t_  = blockIdx.x >> 3;
    const int bq  = t_ & 31;
    const int seg = ((t_ >> 5) << 3) | s8;
    const int qbase  = bq * QB;
    const int cbase0 = seg * SEG_LEN;
    const int l15 = lane & 15, l4 = lane >> 4;

    // stage -0.5 * segment bank norms
    for (int t = tid; t < SEG_LEN / 4; t += 256) {
        float4 v = ((const float4*)(bsqp + cbase0))[t];
        v.x *= -0.5f; v.y *= -0.5f; v.z *= -0.5f; v.w *= -0.5f;
        ((float4*)sm.nsq)[t] = v;
    }

    // query fragments (B operand), cached in registers for the whole block
    bf16x8 qf[4][4];
    float qs4[4];
    int qglob[4], qloc[4];
#pragma unroll
    for (int qt = 0; qt < 4; ++qt) {
        int q = qbase + qw * 64 + qt * 16 + l15;
        qglob[qt] = q;
        qloc[qt]  = qw * 64 + qt * 16 + l15;
        qs4[qt]   = qsqp[q];
#pragma unroll
        for (int ks = 0; ks < 4; ++ks)
            qf[qt][ks] = *(const bf16x8*)(featbf + (size_t)q * D + ks * 32 + l4 * 8);
    }

    float t9[4][K_NEI];
    float g[4];
#pragma unroll
    for (int qt = 0; qt < 4; ++qt) {
        g[qt] = FLT_MAX;
#pragma unroll
        for (int j = 0; j < K_NEI; ++j) t9[qt][j] = FLT_MAX;
    }

#pragma unroll 1
    for (int ch = 0; ch < CHUNKS; ++ch) {
        const int cb = cbase0 + ch * BB;
        __syncthreads();  // all waves done reading previous tile
#pragma unroll
        for (int i = 0; i < 8; ++i) {
            int rgn = wv * 8 + i;
            int bt = rgn >> 2, ks = rgn & 3;
            const __hip_bfloat16* gp =
                bankbf + (size_t)(cb + bt * 16 + l15) * D + ks * 32 + l4 * 8;
            GL_LDS16(gp, &sm.bt[rgn * 512]);
        }
        // refresh gates from device-global thresholds (in flight across MFMA)
        int tg[4];
#pragma unroll
        for (int qt = 0; qt < 4; ++qt)
            tg[qt] = __hip_atomic_load(&thr_g[qglob[qt]], __ATOMIC_RELAXED,
                                       __HIP_MEMORY_SCOPE_AGENT);
        __syncthreads();  // vmcnt drained -> tile ready

        // acc init = -0.5*bs for this chunk's bank rows (D-layout row = l4*4+r)
        floatx4 acc[4][4];
#pragma unroll
        for (int bb = 0; bb < 4; ++bb) {
            floatx4 ini = *(const floatx4*)&sm.nsq[ch * BB + (bw * 4 + bb) * 16 + l4 * 4];
#pragma unroll
            for (int qt = 0; qt < 4; ++qt) acc[bb][qt] = ini;
        }
        // MFMA: 4 bank-tiles x 4 query-tiles, K = 128 (4 ksteps of 32)
#pragma unroll
        for (int ks = 0; ks < 4; ++ks) {
            bf16x8 af[4];
#pragma unroll
            for (int bb = 0; bb < 4; ++bb)
                af[bb] = *(const bf16x8*)&sm.bt[((bw * 4 + bb) * 4 + ks) * 512 + lane * 8];
#pragma unroll
            for (int bb = 0; bb < 4; ++bb)
#pragma unroll
                for (int qt = 0; qt < 4; ++qt)
                    acc[bb][qt] = mfma16(af[bb], qf[qt][ks], acc[bb][qt]);
        }

        // gates -> thresholds on raw acc
        float h[4];
#pragma unroll
        for (int qt = 0; qt < 4; ++qt) {
            g[qt] = fminf(g[qt], __int_as_float(tg[qt]));
            h[qt] = 0.5f * (qs4[qt] - g[qt]);
        }

        // selection: 1 v_cmp per element; rare masked insert path
#pragma unroll
        for (int bb = 0; bb < 4; ++bb) {
#pragma unroll
            for (int qt = 0; qt < 4; ++qt) {
                float a0 = acc[bb][qt][0], a1 = acc[bb][qt][1];
                float a2 = acc[bb][qt][2], a3 = acc[bb][qt][3];
                float mx = fmaxf(fmaxf(a0, a1), fmaxf(a2, a3));
                if (__ballot(mx >= h[qt])) {
#pragma unroll
                    for (int r = 0; r < 4; ++r) {
                        float a = acc[bb][qt][r];
                        if (a >= h[qt]) {
                            float d2 = fmaxf(fmaf(-2.f, a, qs4[qt]), 0.f);
                            if (d2 <= g[qt]) {
                                t9[qt][K_NEI - 1] = d2;
#pragma unroll
                                for (int s = K_NEI - 1; s > 0; --s) {
                                    float lo = fminf(t9[qt][s - 1], t9[qt][s]);
                                    float hi = fmaxf(t9[qt][s - 1], t9[qt][s]);
                                    t9[qt][s - 1] = lo;
                                    t9[qt][s] = hi;
                                }
                                g[qt] = fminf(g[qt], t9[qt][K_NEI - 1]);
                            }
                        }
                    }
                }
            }
        }
        // publish tightened thresholds (float bits monotone for d2 >= 0)
#pragma unroll
        for (int qt = 0; qt < 4; ++qt)
            atomicMin(&thr_g[qglob[qt]], __float_as_int(t9[qt][K_NEI - 1]));
    }

    // ---- epilogue: merge 8 streams (bw x l4) per query -> segment top-9 ----
    __syncthreads();
    int sid = bw * 4 + l4;
#pragma unroll
    for (int qt = 0; qt < 4; ++qt)
#pragma unroll
        for (int j = 0; j < K_NEI; ++j)
            sm.merge[qloc[qt]][sid * K_NEI + j] = t9[qt][j];
    __syncthreads();
    if (tid < QB) {
        const float* row = sm.merge[tid];
        int idx[8] = {0, 0, 0, 0, 0, 0, 0, 0};
        float outv[K_NEI];
#pragma unroll 1
        for (int s = 0; s < K_NEI; ++s) {
            float best = FLT_MAX;
            int bi = 0;
#pragma unroll
            for (int l8 = 0; l8 < 8; ++l8) {
                float v = (idx[l8] < K_NEI) ? row[l8 * K_NEI + idx[l8]] : FLT_MAX;
                if (v < best) { best = v; bi = l8; }
            }
#pragma unroll
            for (int l8 = 0; l8 < 8; ++l8) idx[l8] += (l8 == bi) ? 1 : 0;
            outv[s] = best;
        }
        float* dst = part + ((size_t)(qbase + tid) * SEGS + seg) * K_NEI;
#pragma unroll
        for (int s = 0; s < K_NEI; ++s) dst[s] = outv[s];
    }
}

// ---------------------------------------------------------------------------
// Kernel 3: final merge across segments + sqrt + mean
// ---------------------------------------------------------------------------
__global__ void knn_final(const float* __restrict__ part, float* __restrict__ out) {
    __shared__ float v[64][SEGS * K_NEI];   // 36.9 KB
    int tid = threadIdx.x;
    int q = blockIdx.x * 64 + tid;
    const float* p = part + (size_t)q * (SEGS * K_NEI);
    for (int t = 0; t < SEGS * K_NEI; ++t) v[tid][t] = p[t];
    float sum = 0.f;
    for (int s = 0; s < K_NEI; ++s) {
        float best = FLT_MAX;
        int bi = 0;
        for (int t = 0; t < SEGS * K_NEI; ++t) {
            float x = v[tid][t];
            if (x < best) { best = x; bi = t; }
        }
        v[tid][bi] = FLT_MAX;
        sum += sqrtf(fmaxf(best, 0.f));
    }
    out[q] = sum * (1.0f / 9.0f);
}

// ---------------------------------------------------------------------------
extern "C" void kernel_launch(void* const* d_in, const int* in_sizes, int n_in,
                              void* d_out, int out_size, void* d_ws, size_t ws_size,
                              hipStream_t stream) {
    const float* feats = (const float*)d_in[0];   // [M, D]
    const float* bank  = (const float*)d_in[1];   // [N, D]

    char* w = (char*)d_ws;
    __hip_bfloat16* bankbf = (__hip_bfloat16*)w;                       // 16 MB
    __hip_bfloat16* featbf = (__hip_bfloat16*)(w + (size_t)N * D * 2); // 1 MB
    float* bsqp = (float*)(w + (size_t)(N + M) * D * 2);               // 256 KB
    float* qsqp = bsqp + N;                                            // 16 KB
    float* part = qsqp + M;                                            // 2.25 MB
    int*   thr_g = (int*)(part + (size_t)M * SEGS * K_NEI);            // 16 KB
    float* out  = (float*)d_out;

    // init device-global gates to +big (0x7F7F7F7F = 3.39e38 as float) --
    // ws is re-poisoned 0xAA (negative float bits) before every timed call.
    hipMemsetAsync(thr_g, 0x7F, (size_t)M * sizeof(int), stream);

    prep_kernel<<<N / 4, 256, 0, stream>>>(bank, bankbf, bsqp, N);
    prep_kernel<<<M / 4, 256, 0, stream>>>(feats, featbf, qsqp, M);
    knn_main<<<(M / QB) * SEGS, 256, 0, stream>>>(bankbf, featbf, bsqp, qsqp,
                                                  thr_g, part);
    knn_final<<<M / 64, 64, 0, stream>>>(part, out);
}

// Round 4
// 378.238 us; speedup vs baseline: 1.2681x; 1.2681x over previous
//
#include <hip/hip_runtime.h>
#include <hip/hip_bf16.h>
#include <float.h>

#define K_NEI 9
#define M 4096
#define N 65536
#define D 128
#define SEGS 16
#define SEG_LEN (N / SEGS)     // 4096 bank rows per segment
#define QB 128                 // queries per block
#define BB 128                 // bank rows per chunk
#define CHUNKS (SEG_LEN / BB)  // 32

typedef __bf16 bf16x8 __attribute__((ext_vector_type(8)));
typedef float floatx4 __attribute__((ext_vector_type(4)));

static __device__ inline floatx4 mfma16(bf16x8 a, bf16x8 b, floatx4 c) {
    return __builtin_amdgcn_mfma_f32_16x16x32_bf16(a, b, c, 0, 0, 0);
}

// async global->LDS, 16B per lane, dest = lds_base + lane*16
#define GL_LDS16(gp, lp)                                                     \
    __builtin_amdgcn_global_load_lds(                                        \
        (const __attribute__((address_space(1))) unsigned int*)(const void*)(gp), \
        (__attribute__((address_space(3))) unsigned int*)(void*)(lp), 16, 0, 0)

// ---------------------------------------------------------------------------
// Kernel 1 (fused prep): fp32 -> bf16 convert + row norms for BOTH inputs.
// rows [0,N): bank -> bankbf, bsqn = -0.5*|b|^2 (prescaled for acc init)
// rows [N,N+M): feats -> featbf, qsq = |q|^2, and thr_g[q] = +big (gate init;
//   ws is re-poisoned 0xAA before every timed call, so init here each call).
// ---------------------------------------------------------------------------
__global__ void prep_kernel(const float* __restrict__ bank,
                            const float* __restrict__ feats,
                            __hip_bfloat16* __restrict__ bankbf,
                            __hip_bfloat16* __restrict__ featbf,
                            float* __restrict__ bsqn,
                            float* __restrict__ qsq,
                            int* __restrict__ thr_g) {
    int row  = (int)((blockIdx.x * blockDim.x + threadIdx.x) >> 6);
    int lane = threadIdx.x & 63;
    if (row >= N + M) return;
    const float* src = (row < N) ? (bank + (size_t)row * D)
                                 : (feats + (size_t)(row - N) * D);
    __hip_bfloat16* dst = (row < N) ? (bankbf + (size_t)row * D)
                                    : (featbf + (size_t)(row - N) * D);
    float2 v = ((const float2*)src)[lane];
    float s = v.x * v.x + v.y * v.y;
    dst[lane * 2 + 0] = __float2bfloat16(v.x);
    dst[lane * 2 + 1] = __float2bfloat16(v.y);
#pragma unroll
    for (int off = 32; off > 0; off >>= 1) s += __shfl_down(s, off, 64);
    if (lane == 0) {
        if (row < N) {
            bsqn[row] = -0.5f * s;
        } else {
            qsq[row - N] = s;
            thr_g[row - N] = 0x7f7f7f7f;   // 3.39e38f
        }
    }
}

// ---------------------------------------------------------------------------
// Kernel 2: MFMA distance GEMM + fused per-query top-9 (per bank segment)
// grid = 512 blocks (2/CU, co-resident) of 256 threads (4 waves);
// XCD-swizzled: seg%8 == blockIdx%8 for bank-segment L2 locality.
//
// acc init = -0.5*bs (fp32), so after K=128: acc = dot - 0.5*bs
//   => d2 = qs - 2*acc (exact fp32 norms).
// Gate: d2 <= g  <=>  acc >= h = 0.5*(qs - g): one v_cmp per 4 elements via
// the reg-max, insert body only under ballot. g = min(local t9[8], global
// thr_g[q]); thr_g published via cross-lane-reduced, dirty-skipped atomicMin
// from 16 lanes every 2nd chunk (round-3 lesson: 64-lane/chunk atomics =
// 116 MB of cross-XCD write traffic).
// Single barrier per chunk: double-buffered bank tile, loads for ch+1 issued
// right after the barrier -> full-body latency to land before next drain.
// ---------------------------------------------------------------------------
__global__ __launch_bounds__(256, 2)
void knn_main(const __hip_bfloat16* __restrict__ bankbf,
              const __hip_bfloat16* __restrict__ featbf,
              const float* __restrict__ bsqn,
              const float* __restrict__ qsqp,
              int* __restrict__ thr_g,
              float* __restrict__ part) {
    __shared__ __align__(16) union SMEM {
        short bt[2][32 * 512];       // 2 x 32 KB bank tile (double buffer)
        float merge[QB][8 * K_NEI];  // 36.9 KB epilogue merge buffer
    } sm;

    const int tid  = threadIdx.x;
    const int lane = tid & 63;
    const int wv   = tid >> 6;
    const int qw   = wv & 1;        // query half of block
    const int bw   = wv >> 1;       // bank half of chunk
    // XCD swizzle: seg%8 == blockIdx%8
    const int s8  = blockIdx.x & 7;
    const int t_  = blockIdx.x >> 3;
    const int bq  = t_ & 31;
    const int seg = ((t_ >> 5) << 3) | s8;
    const int qbase  = bq * QB;
    const int cbase0 = seg * SEG_LEN;
    const int l15 = lane & 15, l4 = lane >> 4;

    // query fragments (B operand), cached in registers for the whole block
    bf16x8 qf[4][4];
    float qs4[4];
    int qglob[4], qloc[4];
#pragma unroll
    for (int qt = 0; qt < 4; ++qt) {
        int q = qbase + qw * 64 + qt * 16 + l15;
        qglob[qt] = q;
        qloc[qt]  = qw * 64 + qt * 16 + l15;
        qs4[qt]   = qsqp[q];
#pragma unroll
        for (int ks = 0; ks < 4; ++ks)
            qf[qt][ks] = *(const bf16x8*)(featbf + (size_t)q * D + ks * 32 + l4 * 8);
    }

    float t9[4][K_NEI];
    float g[4], lastpub[4];
#pragma unroll
    for (int qt = 0; qt < 4; ++qt) {
        g[qt] = FLT_MAX;
        lastpub[qt] = FLT_MAX;
#pragma unroll
        for (int j = 0; j < K_NEI; ++j) t9[qt][j] = FLT_MAX;
    }

    // prologue: stage chunk 0 into buffer 0
#pragma unroll
    for (int i = 0; i < 8; ++i) {
        int rgn = wv * 8 + i;
        int bt = rgn >> 2, ks = rgn & 3;
        const __hip_bfloat16* gp =
            bankbf + (size_t)(cbase0 + bt * 16 + l15) * D + ks * 32 + l4 * 8;
        GL_LDS16(gp, &sm.bt[0][rgn * 512]);
    }

#pragma unroll 1
    for (int ch = 0; ch < CHUNKS; ++ch) {
        const int cur = ch & 1;
        __syncthreads();  // drains own vmcnt -> buf[cur] ready; buf[cur^1] free

        // issue next chunk's staging immediately (lands during this body)
        if (ch + 1 < CHUNKS) {
            const int cb1 = cbase0 + (ch + 1) * BB;
#pragma unroll
            for (int i = 0; i < 8; ++i) {
                int rgn = wv * 8 + i;
                int bt = rgn >> 2, ks = rgn & 3;
                const __hip_bfloat16* gp =
                    bankbf + (size_t)(cb1 + bt * 16 + l15) * D + ks * 32 + l4 * 8;
                GL_LDS16(gp, &sm.bt[cur ^ 1][rgn * 512]);
            }
        }
        // refresh gates from device-global thresholds (consumed after MFMA)
        int tg[4];
#pragma unroll
        for (int qt = 0; qt < 4; ++qt)
            tg[qt] = __hip_atomic_load(&thr_g[qglob[qt]], __ATOMIC_RELAXED,
                                       __HIP_MEMORY_SCOPE_AGENT);

        // acc init = -0.5*bs for this chunk's rows (D-layout row = l4*4+r);
        // 16 floats per bb, L1-resident (16 KB segment norms)
        const int cb = cbase0 + ch * BB;
        floatx4 acc[4][4];
#pragma unroll
        for (int bb = 0; bb < 4; ++bb) {
            floatx4 ini = *(const floatx4*)&bsqn[cb + (bw * 4 + bb) * 16 + l4 * 4];
#pragma unroll
            for (int qt = 0; qt < 4; ++qt) acc[bb][qt] = ini;
        }
        // MFMA: 4 bank-tiles x 4 query-tiles, K = 128 (4 ksteps of 32)
#pragma unroll
        for (int ks = 0; ks < 4; ++ks) {
            bf16x8 af[4];
#pragma unroll
            for (int bb = 0; bb < 4; ++bb)
                af[bb] = *(const bf16x8*)
                    &sm.bt[cur][((bw * 4 + bb) * 4 + ks) * 512 + lane * 8];
#pragma unroll
            for (int bb = 0; bb < 4; ++bb)
#pragma unroll
                for (int qt = 0; qt < 4; ++qt)
                    acc[bb][qt] = mfma16(af[bb], qf[qt][ks], acc[bb][qt]);
        }

        // gates -> thresholds on raw acc (tiny loosening guards rounding of
        // the d2<->acc transform at exact-tie boundaries)
        float h[4];
#pragma unroll
        for (int qt = 0; qt < 4; ++qt) {
            g[qt] = fminf(g[qt], __int_as_float(tg[qt]));
            h[qt] = 0.5f * (qs4[qt] - g[qt] * 1.0000005f);
        }

        // selection: 1 reg-max + 1 v_cmp per 4 elements; rare insert path
#pragma unroll
        for (int bb = 0; bb < 4; ++bb) {
#pragma unroll
            for (int qt = 0; qt < 4; ++qt) {
                float a0 = acc[bb][qt][0], a1 = acc[bb][qt][1];
                float a2 = acc[bb][qt][2], a3 = acc[bb][qt][3];
                float mx = fmaxf(fmaxf(a0, a1), fmaxf(a2, a3));
                if (__ballot(mx >= h[qt])) {
#pragma unroll
                    for (int r = 0; r < 4; ++r) {
                        float a = acc[bb][qt][r];
                        if (a >= h[qt]) {
                            float d2 = fmaxf(fmaf(-2.f, a, qs4[qt]), 0.f);
                            if (d2 <= g[qt]) {
                                t9[qt][K_NEI - 1] = d2;
#pragma unroll
                                for (int s = K_NEI - 1; s > 0; --s) {
                                    float lo = fminf(t9[qt][s - 1], t9[qt][s]);
                                    float hi = fmaxf(t9[qt][s - 1], t9[qt][s]);
                                    t9[qt][s - 1] = lo;
                                    t9[qt][s] = hi;
                                }
                                g[qt] = fminf(g[qt], t9[qt][K_NEI - 1]);
                            }
                        }
                    }
                }
            }
        }
        // publish: cross-lane min over the 4 partner lanes (l4), 16 lanes,
        // every 2nd chunk, only if improved since last publish
        if (ch & 1) {
#pragma unroll
            for (int qt = 0; qt < 4; ++qt) {
                float m = t9[qt][K_NEI - 1];
                m = fminf(m, __shfl_xor(m, 16, 64));
                m = fminf(m, __shfl_xor(m, 32, 64));
                if (l4 == 0 && m < lastpub[qt]) {
                    atomicMin(&thr_g[qglob[qt]], __float_as_int(m));
                    lastpub[qt] = m;
                }
            }
        }
    }

    // ---- epilogue: merge 8 streams (bw x l4) per query -> segment top-9 ----
    __syncthreads();
    int sid = bw * 4 + l4;
#pragma unroll
    for (int qt = 0; qt < 4; ++qt)
#pragma unroll
        for (int j = 0; j < K_NEI; ++j)
            sm.merge[qloc[qt]][sid * K_NEI + j] = t9[qt][j];
    __syncthreads();
    if (tid < QB) {
        const float* row = sm.merge[tid];
        int idx[8] = {0, 0, 0, 0, 0, 0, 0, 0};
        float outv[K_NEI];
#pragma unroll 1
        for (int s = 0; s < K_NEI; ++s) {
            float best = FLT_MAX;
            int bi = 0;
#pragma unroll
            for (int l8 = 0; l8 < 8; ++l8) {
                float v = (idx[l8] < K_NEI) ? row[l8 * K_NEI + idx[l8]] : FLT_MAX;
                if (v < best) { best = v; bi = l8; }
            }
#pragma unroll
            for (int l8 = 0; l8 < 8; ++l8) idx[l8] += (l8 == bi) ? 1 : 0;
            outv[s] = best;
        }
        float* dst = part + ((size_t)(qbase + tid) * SEGS + seg) * K_NEI;
#pragma unroll
        for (int s = 0; s < K_NEI; ++s) dst[s] = outv[s];
    }
}

// ---------------------------------------------------------------------------
// Kernel 3: final merge across segments + sqrt + mean
// ---------------------------------------------------------------------------
__global__ void knn_final(const float* __restrict__ part, float* __restrict__ out) {
    __shared__ float v[64][SEGS * K_NEI];   // 36.9 KB
    int tid = threadIdx.x;
    int q = blockIdx.x * 64 + tid;
    const float* p = part + (size_t)q * (SEGS * K_NEI);
    for (int t = 0; t < SEGS * K_NEI; ++t) v[tid][t] = p[t];
    float sum = 0.f;
    for (int s = 0; s < K_NEI; ++s) {
        float best = FLT_MAX;
        int bi = 0;
        for (int t = 0; t < SEGS * K_NEI; ++t) {
            float x = v[tid][t];
            if (x < best) { best = x; bi = t; }
        }
        v[tid][bi] = FLT_MAX;
        sum += sqrtf(fmaxf(best, 0.f));
    }
    out[q] = sum * (1.0f / 9.0f);
}

// ---------------------------------------------------------------------------
extern "C" void kernel_launch(void* const* d_in, const int* in_sizes, int n_in,
                              void* d_out, int out_size, void* d_ws, size_t ws_size,
                              hipStream_t stream) {
    const float* feats = (const float*)d_in[0];   // [M, D]
    const float* bank  = (const float*)d_in[1];   // [N, D]

    char* w = (char*)d_ws;
    __hip_bfloat16* bankbf = (__hip_bfloat16*)w;                       // 16 MB
    __hip_bfloat16* featbf = (__hip_bfloat16*)(w + (size_t)N * D * 2); // 1 MB
    float* bsqn = (float*)(w + (size_t)(N + M) * D * 2);               // 256 KB
    float* qsqp = bsqn + N;                                            // 16 KB
    float* part = qsqp + M;                                            // 2.25 MB
    int*   thr_g = (int*)(part + (size_t)M * SEGS * K_NEI);            // 16 KB
    float* out  = (float*)d_out;

    prep_kernel<<<(N + M) / 4, 256, 0, stream>>>(bank, feats, bankbf, featbf,
                                                 bsqn, qsqp, thr_g);
    knn_main<<<(M / QB) * SEGS, 256, 0, stream>>>(bankbf, featbf, bsqn, qsqp,
                                                  thr_g, part);
    knn_final<<<M / 64, 64, 0, stream>>>(part, out);
}

// Round 6
// 367.349 us; speedup vs baseline: 1.3057x; 1.0296x over previous
//
#include <hip/hip_runtime.h>
#include <hip/hip_bf16.h>
#include <float.h>

#define K_NEI 9
#define M 4096
#define N 65536
#define D 128
#define SEGS 16
#define SEG_LEN (N / SEGS)     // 4096 bank rows per segment
#define QB 128                 // queries per block
#define BB 128                 // bank rows per chunk
#define CHUNKS (SEG_LEN / BB)  // 32
#define QGROUPS (M / QB)       // 32

typedef __bf16 bf16x8 __attribute__((ext_vector_type(8)));
typedef float floatx4 __attribute__((ext_vector_type(4)));

static __device__ inline floatx4 mfma16(bf16x8 a, bf16x8 b, floatx4 c) {
    return __builtin_amdgcn_mfma_f32_16x16x32_bf16(a, b, c, 0, 0, 0);
}

// async global->LDS, 16B per lane, dest = lds_base + lane*16
#define GL_LDS16(gp, lp)                                                     \
    __builtin_amdgcn_global_load_lds(                                        \
        (const __attribute__((address_space(1))) unsigned int*)(const void*)(gp), \
        (__attribute__((address_space(3))) unsigned int*)(void*)(lp), 16, 0, 0)

// ---- sorted-9 toolkit -----------------------------------------------------
static __device__ inline void ce(float& a, float& b) {
    float lo = fminf(a, b), hi = fmaxf(a, b); a = lo; b = hi;
}
// canonical optimal 25-CE / depth-7 sorting network for 9 (ascending)
static __device__ inline void sort9(float t[K_NEI]) {
    ce(t[0],t[3]); ce(t[1],t[7]); ce(t[2],t[5]); ce(t[4],t[8]);
    ce(t[0],t[7]); ce(t[2],t[4]); ce(t[3],t[8]); ce(t[5],t[6]);
    ce(t[0],t[2]); ce(t[1],t[3]); ce(t[4],t[5]); ce(t[7],t[8]);
    ce(t[1],t[4]); ce(t[3],t[6]); ce(t[5],t[7]);
    ce(t[0],t[1]); ce(t[2],t[4]); ce(t[3],t[5]); ce(t[6],t[8]);
    ce(t[2],t[3]); ce(t[4],t[5]); ce(t[6],t[7]);
    ce(t[1],t[2]); ce(t[3],t[4]); ce(t[5],t[6]);
}
// t, o sorted ascending -> t = sorted 9 smallest of union (bitonic min trick)
static __device__ inline void merge9(float t[K_NEI], const float o[K_NEI]) {
    float m[K_NEI];
#pragma unroll
    for (int i = 0; i < K_NEI; ++i) m[i] = fminf(t[i], o[K_NEI - 1 - i]);
    sort9(m);
#pragma unroll
    for (int i = 0; i < K_NEI; ++i) t[i] = m[i];
}
// pool the 4 partner lanes (lane ^16, ^32): all 4 end with identical exact
// top-9 of the quad's union. ONLY valid if the 4 lists are element-disjoint.
static __device__ inline void quad_merge(float t[K_NEI]) {
    float o[K_NEI];
#pragma unroll
    for (int i = 0; i < K_NEI; ++i) o[i] = __shfl_xor(t[i], 16, 64);
    merge9(t, o);
#pragma unroll
    for (int i = 0; i < K_NEI; ++i) o[i] = __shfl_xor(t[i], 32, 64);
    merge9(t, o);
}

// ---------------------------------------------------------------------------
// Kernel 1 (fused prep): fp32 -> bf16 convert + row norms for BOTH inputs,
// plus per-call init of thr_g (gates) and done (qgroup counters) -- ws is
// re-poisoned 0xAA before every timed call.
// ---------------------------------------------------------------------------
__global__ void prep_kernel(const float* __restrict__ bank,
                            const float* __restrict__ feats,
                            __hip_bfloat16* __restrict__ bankbf,
                            __hip_bfloat16* __restrict__ featbf,
                            float* __restrict__ bsqn,
                            float* __restrict__ qsq,
                            int* __restrict__ thr_g,
                            int* __restrict__ done) {
    int row  = (int)((blockIdx.x * blockDim.x + threadIdx.x) >> 6);
    int lane = threadIdx.x & 63;
    if (row >= N + M) return;
    const float* src = (row < N) ? (bank + (size_t)row * D)
                                 : (feats + (size_t)(row - N) * D);
    __hip_bfloat16* dst = (row < N) ? (bankbf + (size_t)row * D)
                                    : (featbf + (size_t)(row - N) * D);
    float2 v = ((const float2*)src)[lane];
    float s = v.x * v.x + v.y * v.y;
    dst[lane * 2 + 0] = __float2bfloat16(v.x);
    dst[lane * 2 + 1] = __float2bfloat16(v.y);
#pragma unroll
    for (int off = 32; off > 0; off >>= 1) s += __shfl_down(s, off, 64);
    if (lane == 0) {
        if (row < N) {
            bsqn[row] = -0.5f * s;
        } else {
            qsq[row - N] = s;
            thr_g[row - N] = 0x7f7f7f7f;   // 3.39e38f
        }
    }
    if (lane == 1 && row >= N && row < N + QGROUPS) done[row - N] = 0;
}

// ---------------------------------------------------------------------------
// Kernel 2: MFMA distance GEMM + fused per-query top-9 + fused final merge.
// grid = 512 blocks (2/CU, co-resident) of 256 threads (4 waves);
// XCD-swizzled: seg%8 == blockIdx%8 for bank-segment L2 locality.
//
// acc init = -0.5*bs (fp32) => acc = dot - 0.5*bs => d2 = qs - 2*acc.
// Gate: d2 <= g  <=>  acc >= h = 0.5*(qs - g): 1 reg-max + 1 v_cmp per 4
// elements.
// Gate-merge events (ch = 0,1,3,7,15,23): each 4-lane quad computes its
// EXACT pooled top-9 and publishes the pooled 9th (atomicMin, dirty-skip).
// ROUND-5 BUG FIX: after the event, only the l4==0 leader KEEPS the pooled
// list; the other 3 lanes reset to +INF. This keeps the 4 lists element-
// disjoint (leader holds history, followers hold only post-event inserts),
// so the next event's pool and the epilogue pool count every candidate
// exactly once. Round 5 let all 4 lanes keep identical copies -> the next
// pool counted each element 4x -> the published "9th" was really the ~3rd
// -> over-tight gate pruned true neighbors (absmax 1.06).
// Last seg-block per qgroup (done-counter + threadfence + agent-scope loads)
// folds the 16 sorted per-seg lists and writes the output -- no 3rd kernel.
// ---------------------------------------------------------------------------
__global__ __launch_bounds__(256, 2)
void knn_main(const __hip_bfloat16* __restrict__ bankbf,
              const __hip_bfloat16* __restrict__ featbf,
              const float* __restrict__ bsqn,
              const float* __restrict__ qsqp,
              int* __restrict__ thr_g,
              float* __restrict__ part,
              int* __restrict__ done,
              float* __restrict__ out) {
    __shared__ __align__(16) union SMEM {
        short bt[2][32 * 512];       // 2 x 32 KB bank tile (double buffer)
        float pool[QB][K_NEI];       // 4.6 KB epilogue cross-wave pool
    } sm;
    __shared__ int sm_last;

    const int tid  = threadIdx.x;
    const int lane = tid & 63;
    const int wv   = tid >> 6;
    const int qw   = wv & 1;        // query half of block
    const int bw   = wv >> 1;       // bank half of chunk
    // XCD swizzle: seg%8 == blockIdx%8
    const int s8  = blockIdx.x & 7;
    const int t_  = blockIdx.x >> 3;
    const int bq  = t_ & 31;
    const int seg = ((t_ >> 5) << 3) | s8;
    const int qbase  = bq * QB;
    const int cbase0 = seg * SEG_LEN;
    const int l15 = lane & 15, l4 = lane >> 4;

    // query fragments (B operand), cached in registers for the whole block
    bf16x8 qf[4][4];
    float qs4[4];
    int qglob[4], qloc[4];
#pragma unroll
    for (int qt = 0; qt < 4; ++qt) {
        int q = qbase + qw * 64 + qt * 16 + l15;
        qglob[qt] = q;
        qloc[qt]  = qw * 64 + qt * 16 + l15;
        qs4[qt]   = qsqp[q];
#pragma unroll
        for (int ks = 0; ks < 4; ++ks)
            qf[qt][ks] = *(const bf16x8*)(featbf + (size_t)q * D + ks * 32 + l4 * 8);
    }

    float t9[4][K_NEI];
    float g[4], lastpub[4];
#pragma unroll
    for (int qt = 0; qt < 4; ++qt) {
        g[qt] = FLT_MAX;
        lastpub[qt] = FLT_MAX;
#pragma unroll
        for (int j = 0; j < K_NEI; ++j) t9[qt][j] = FLT_MAX;
    }

    // prologue: stage chunk 0 into buffer 0
#pragma unroll
    for (int i = 0; i < 8; ++i) {
        int rgn = wv * 8 + i;
        int bt = rgn >> 2, ks = rgn & 3;
        const __hip_bfloat16* gp =
            bankbf + (size_t)(cbase0 + bt * 16 + l15) * D + ks * 32 + l4 * 8;
        GL_LDS16(gp, &sm.bt[0][rgn * 512]);
    }

#pragma unroll 1
    for (int ch = 0; ch < CHUNKS; ++ch) {
        const int cur = ch & 1;
        __syncthreads();  // drains own vmcnt -> buf[cur] ready; buf[cur^1] free

        // issue next chunk's staging immediately (lands during this body)
        if (ch + 1 < CHUNKS) {
            const int cb1 = cbase0 + (ch + 1) * BB;
#pragma unroll
            for (int i = 0; i < 8; ++i) {
                int rgn = wv * 8 + i;
                int bt = rgn >> 2, ks = rgn & 3;
                const __hip_bfloat16* gp =
                    bankbf + (size_t)(cb1 + bt * 16 + l15) * D + ks * 32 + l4 * 8;
                GL_LDS16(gp, &sm.bt[cur ^ 1][rgn * 512]);
            }
        }
        // refresh gates from device-global thresholds (consumed after MFMA)
        int tg[4];
#pragma unroll
        for (int qt = 0; qt < 4; ++qt)
            tg[qt] = __hip_atomic_load(&thr_g[qglob[qt]], __ATOMIC_RELAXED,
                                       __HIP_MEMORY_SCOPE_AGENT);

        // acc init = -0.5*bs for this chunk's rows (D-layout row = l4*4+r)
        const int cb = cbase0 + ch * BB;
        floatx4 acc[4][4];
#pragma unroll
        for (int bb = 0; bb < 4; ++bb) {
            floatx4 ini = *(const floatx4*)&bsqn[cb + (bw * 4 + bb) * 16 + l4 * 4];
#pragma unroll
            for (int qt = 0; qt < 4; ++qt) acc[bb][qt] = ini;
        }
        // MFMA: 4 bank-tiles x 4 query-tiles, K = 128 (4 ksteps of 32)
#pragma unroll
        for (int ks = 0; ks < 4; ++ks) {
            bf16x8 af[4];
#pragma unroll
            for (int bb = 0; bb < 4; ++bb)
                af[bb] = *(const bf16x8*)
                    &sm.bt[cur][((bw * 4 + bb) * 4 + ks) * 512 + lane * 8];
#pragma unroll
            for (int bb = 0; bb < 4; ++bb)
#pragma unroll
                for (int qt = 0; qt < 4; ++qt)
                    acc[bb][qt] = mfma16(af[bb], qf[qt][ks], acc[bb][qt]);
        }

        // gates -> thresholds on raw acc (loosening guards transform rounding)
        float h[4];
#pragma unroll
        for (int qt = 0; qt < 4; ++qt) {
            g[qt] = fminf(g[qt], __int_as_float(tg[qt]));
            h[qt] = 0.5f * (qs4[qt] - g[qt] * 1.0000005f);
        }

        // selection: 1 reg-max + 1 v_cmp per 4 elements; rare insert path
#pragma unroll
        for (int bb = 0; bb < 4; ++bb) {
#pragma unroll
            for (int qt = 0; qt < 4; ++qt) {
                float a0 = acc[bb][qt][0], a1 = acc[bb][qt][1];
                float a2 = acc[bb][qt][2], a3 = acc[bb][qt][3];
                float mx = fmaxf(fmaxf(a0, a1), fmaxf(a2, a3));
                if (__ballot(mx >= h[qt])) {
#pragma unroll
                    for (int r = 0; r < 4; ++r) {
                        float a = acc[bb][qt][r];
                        if (a >= h[qt]) {
                            float d2 = fmaxf(fmaf(-2.f, a, qs4[qt]), 0.f);
                            if (d2 <= g[qt]) {
                                t9[qt][K_NEI - 1] = d2;
#pragma unroll
                                for (int s = K_NEI - 1; s > 0; --s)
                                    ce(t9[qt][s - 1], t9[qt][s]);
                                g[qt] = fminf(g[qt], t9[qt][K_NEI - 1]);
                            }
                        }
                    }
                }
            }
        }
        // gate-merge events (ch = 0,1,3,7,15,23 -> mask 0x80808B):
        // exact quad pool -> publish 9th; leader keeps, followers clear.
        if ((0x80808Bu >> ch) & 1) {
#pragma unroll
            for (int qt = 0; qt < 4; ++qt) {
                quad_merge(t9[qt]);
                float nth = t9[qt][K_NEI - 1];
                g[qt] = fminf(g[qt], nth);
                if (l4 == 0) {
                    if (nth < lastpub[qt]) {
                        atomicMin(&thr_g[qglob[qt]], __float_as_int(nth));
                        lastpub[qt] = nth;
                    }
                } else {
                    // follower: reset so lists stay element-disjoint
#pragma unroll
                    for (int j = 0; j < K_NEI; ++j) t9[qt][j] = FLT_MAX;
                }
            }
        }
    }

    // ---- epilogue: pool quad (disjoint), then cross-wave (bw) via LDS -----
#pragma unroll
    for (int qt = 0; qt < 4; ++qt) quad_merge(t9[qt]);
    __syncthreads();            // last chunk's ds_reads done; bt area reusable
    if (bw == 0 && l4 == 0) {
#pragma unroll
        for (int qt = 0; qt < 4; ++qt)
#pragma unroll
            for (int j = 0; j < K_NEI; ++j)
                sm.pool[qloc[qt]][j] = t9[qt][j];
    }
    __syncthreads();
    if (bw == 1 && l4 == 0) {
#pragma unroll
        for (int qt = 0; qt < 4; ++qt) {
            float o[K_NEI];
#pragma unroll
            for (int j = 0; j < K_NEI; ++j) o[j] = sm.pool[qloc[qt]][j];
            merge9(t9[qt], o);   // block-pooled sorted top-9 for this segment
            float* dst = part + ((size_t)(qbase + qloc[qt]) * SEGS + seg) * K_NEI;
#pragma unroll
            for (int j = 0; j < K_NEI; ++j) dst[j] = t9[qt][j];
        }
    }

    // ---- fused final: last seg-block of this qgroup folds 16 sorted lists --
    __threadfence();            // release our part writes device-wide
    __syncthreads();
    if (tid == 0)
        sm_last = (atomicAdd(&done[bq], 1) == SEGS - 1) ? 1 : 0;
    __syncthreads();
    if (sm_last && tid < QB) {
        int q = qbase + tid;
        const float* p = part + (size_t)q * SEGS * K_NEI;
        float R[K_NEI], nx[K_NEI];
#pragma unroll
        for (int j = 0; j < K_NEI; ++j)
            R[j] = __hip_atomic_load(p + j, __ATOMIC_RELAXED,
                                     __HIP_MEMORY_SCOPE_AGENT);
#pragma unroll
        for (int j = 0; j < K_NEI; ++j)
            nx[j] = __hip_atomic_load(p + K_NEI + j, __ATOMIC_RELAXED,
                                      __HIP_MEMORY_SCOPE_AGENT);
#pragma unroll 1
        for (int s = 1; s < SEGS; ++s) {
            float o[K_NEI];
#pragma unroll
            for (int j = 0; j < K_NEI; ++j) o[j] = nx[j];
            if (s + 1 < SEGS) {
#pragma unroll
                for (int j = 0; j < K_NEI; ++j)
                    nx[j] = __hip_atomic_load(p + (s + 1) * K_NEI + j,
                                              __ATOMIC_RELAXED,
                                              __HIP_MEMORY_SCOPE_AGENT);
            }
            merge9(R, o);
        }
        float sum = 0.f;
#pragma unroll
        for (int j = 0; j < K_NEI; ++j) sum += sqrtf(fmaxf(R[j], 0.f));
        out[q] = sum * (1.0f / 9.0f);
    }
}

// ---------------------------------------------------------------------------
extern "C" void kernel_launch(void* const* d_in, const int* in_sizes, int n_in,
                              void* d_out, int out_size, void* d_ws, size_t ws_size,
                              hipStream_t stream) {
    const float* feats = (const float*)d_in[0];   // [M, D]
    const float* bank  = (const float*)d_in[1];   // [N, D]

    char* w = (char*)d_ws;
    __hip_bfloat16* bankbf = (__hip_bfloat16*)w;                       // 16 MB
    __hip_bfloat16* featbf = (__hip_bfloat16*)(w + (size_t)N * D * 2); // 1 MB
    float* bsqn = (float*)(w + (size_t)(N + M) * D * 2);               // 256 KB
    float* qsqp = bsqn + N;                                            // 16 KB
    float* part = qsqp + M;                                            // 2.25 MB
    int*   thr_g = (int*)(part + (size_t)M * SEGS * K_NEI);            // 16 KB
    int*   done  = thr_g + M;                                          // 128 B
    float* out  = (float*)d_out;

    prep_kernel<<<(N + M) / 4, 256, 0, stream>>>(bank, feats, bankbf, featbf,
                                                 bsqn, qsqp, thr_g, done);
    knn_main<<<(M / QB) * SEGS, 256, 0, stream>>>(bankbf, featbf, bsqn, qsqp,
                                                  thr_g, part, done, out);
}